// Round 10
// baseline (976.932 us; speedup 1.0000x reference)
//
#include <hip/hip_runtime.h>
#include <hip/hip_bf16.h>

#define N_TOK 2048
#define HIDDEN 5120
#define HEAD_DIM 128
#define HQ 40
#define HKV 8
#define QKV_OUT 7208
#define Q_SIZE 5120
#define KV_SIZE 1024

typedef __attribute__((ext_vector_type(8))) short bf16x8;
typedef __attribute__((ext_vector_type(4))) float f32x4;
typedef __attribute__((ext_vector_type(4))) unsigned short us4;

__device__ inline unsigned short f2bf(float f) {
    return __builtin_bit_cast(unsigned short, __float2bfloat16(f));
}
__device__ inline float bf2f(unsigned short s) {
    unsigned u = ((unsigned)s) << 16;
    return __builtin_bit_cast(float, u);
}
__device__ inline f32x4 mfma16(bf16x8 a, bf16x8 b, f32x4 c) {
    return __builtin_amdgcn_mfma_f32_16x16x32_bf16(a, b, c, 0, 0, 0);
}
__device__ inline void gl16(const void* g, void* l) {
    __builtin_amdgcn_global_load_lds((__attribute__((address_space(1))) void*)g,
                                     (__attribute__((address_space(3))) void*)l, 16, 0, 0);
}

// ---------------- sort tokens by modality (stable) ----------------
__global__ void k_sort(const int* __restrict__ mids_raw, int* __restrict__ meta,
                       int* __restrict__ perm) {
    int l = threadIdx.x;  // 64 threads, 1 wave
    int oddnz = 0;
    for (int c = 0; c < 32; ++c) {
        int idx = c * 64 + l;
        int v = mids_raw[idx];
        if ((idx & 1) && v != 0) oddnz = 1;
    }
    bool is64 = (__ballot(oddnz) == 0ULL);
    int c0 = 0, c1 = 0;
    for (int c = 0; c < 32; ++c) {
        int i = c * 64 + l;
        int m = is64 ? mids_raw[2 * i] : mids_raw[i];
        c0 += (m == 0); c1 += (m == 1);
    }
    for (int o = 32; o; o >>= 1) { c0 += __shfl_xor(c0, o); c1 += __shfl_xor(c1, o); }
    if (l == 0) { meta[0] = 0; meta[1] = c0; meta[2] = c0 + c1; meta[3] = N_TOK; }
    int r0 = 0, r1 = c0, r2 = c0 + c1;
    unsigned long long below = (1ULL << l) - 1ULL;
    for (int c = 0; c < 32; ++c) {
        int i = c * 64 + l;
        int m = is64 ? mids_raw[2 * i] : mids_raw[i];
        unsigned long long b0 = __ballot(m == 0), b1 = __ballot(m == 1), b2 = __ballot(m == 2);
        int pos = (m == 0) ? r0 + __popcll(b0 & below)
                : (m == 1) ? r1 + __popcll(b1 & below)
                           : r2 + __popcll(b2 & below);
        perm[pos] = i;
        r0 += __popcll(b0); r1 += __popcll(b1); r2 += __popcll(b2);
    }
}

// ---------------- weight fp32 -> bf16 conversion ----------------
__global__ __launch_bounds__(256) void k_cvt(const float* __restrict__ src,
                                             unsigned short* __restrict__ dst, int n8) {
    int i = blockIdx.x * 256 + threadIdx.x;
    int stride = gridDim.x * 256;
    for (; i < n8; i += stride) {
        float4 a = ((const float4*)src)[2 * i];
        float4 b = ((const float4*)src)[2 * i + 1];
        bf16x8 o;
        o[0] = (short)f2bf(a.x); o[1] = (short)f2bf(a.y);
        o[2] = (short)f2bf(a.z); o[3] = (short)f2bf(a.w);
        o[4] = (short)f2bf(b.x); o[5] = (short)f2bf(b.y);
        o[6] = (short)f2bf(b.z); o[7] = (short)f2bf(b.w);
        ((bf16x8*)dst)[i] = o;
    }
}

// ---------------- pre-norm ----------------
__global__ __launch_bounds__(256) void k_prenorm(const float* __restrict__ hidden,
        const float* __restrict__ pnw, const int* __restrict__ meta,
        const int* __restrict__ perm, unsigned short* __restrict__ h) {
    int i = blockIdx.x;
    int m = (i >= meta[1]) + (i >= meta[2]);
    int t = perm[i];
    const float4* x = (const float4*)(hidden + (size_t)t * HIDDEN);
    const float4* wv = (const float4*)(pnw + (size_t)m * HIDDEN);
    int tid = threadIdx.x;
    float4 xv[5];
    float ss = 0.f;
#pragma unroll
    for (int j = 0; j < 5; ++j) {
        xv[j] = x[tid + j * 256];
        ss += xv[j].x * xv[j].x + xv[j].y * xv[j].y + xv[j].z * xv[j].z + xv[j].w * xv[j].w;
    }
    for (int o = 32; o; o >>= 1) ss += __shfl_xor(ss, o);
    __shared__ float red[4];
    if ((tid & 63) == 0) red[tid >> 6] = ss;
    __syncthreads();
    float rms = rsqrtf((red[0] + red[1] + red[2] + red[3]) * (1.f / HIDDEN) + 1e-6f);
    us4* dst = (us4*)(h + (size_t)i * HIDDEN);
#pragma unroll
    for (int j = 0; j < 5; ++j) {
        float4 w = wv[tid + j * 256];
        us4 o4;
        o4.x = f2bf(xv[j].x * rms * (w.x + 1.f));
        o4.y = f2bf(xv[j].y * rms * (w.y + 1.f));
        o4.z = f2bf(xv[j].z * rms * (w.z + 1.f));
        o4.w = f2bf(xv[j].w * rms * (w.w + 1.f));
        dst[tid + j * 256] = o4;
    }
}

// ------ 128x128 MoE GEMM, BK=32, 4-buffer counted-vmcnt pipeline (never drains) ------
// C[i,j] = sum_k A[i,k]*B[m,j,k]; A,B bf16 (gl16-staged, pre-swizzled source).
// 4 waves (2x2 of 64x64). Buffer = one K-tile (A 8KB + B 8KB) x 4 = 64 KiB ->
// 2 blocks/CU. Per lane per K-tile: 4 gl16. Steady state: 3 tiles in flight;
// per iter: vmcnt(8)+lgkmcnt(0) [tile kt landed, kt+1/kt+2 flying] -> barrier ->
// STAGE(kt+3) -> COMPUTE(kt). Single barrier per K-tile; tail peels vmcnt(4)/(0).
template <int NOUT, bool SCATTER>
__global__ __launch_bounds__(256, 2) void k_gemm(
        const unsigned short* __restrict__ A, const unsigned short* __restrict__ Bw,
        unsigned short* __restrict__ outB, float* __restrict__ outF,
        const int* __restrict__ meta, const int* __restrict__ perm,
        int nx, int ny) {
    // bijective chunked XCD swizzle (m204); tx fastest -> same-panel blocks co-XCD
    int nwg = nx * ny * 3;
    int bid = blockIdx.x;
    int xcd = bid & 7, o = bid >> 3;
    int q = nwg >> 3, r = nwg & 7;
    int swz = (xcd < r ? xcd * (q + 1) : r * (q + 1) + (xcd - r) * q) + o;
    int mz = swz / (nx * ny);
    int rest = swz - mz * (nx * ny);
    int ty = rest / nx, tx = rest - ty * nx;

    int rowS = meta[mz], rowE = meta[mz + 1];
    int row0 = rowS + tx * 128;
    if (row0 >= rowE) return;
    int col0 = ty * 128;
    const unsigned short* Bm = Bw + (size_t)mz * NOUT * HIDDEN;

    // 4 buffers x [A 8KB | B 8KB]
    __shared__ __align__(16) char smem[65536];
    int tid = threadIdx.x, l = tid & 63, w = tid >> 6;
    int wr = (w >> 1) * 64, wc = (w & 1) * 64;

    f32x4 acc[4][4] = {};

    // Staging: K-tile = 128 rows x 32 K bf16 (64B/row). Round j (0..1) covers
    // rows 64j..+63; wave w rows 16w..+15; lane: lr=l>>2 (row in wave slice),
    // lc=l&3 (16B chunk). Source chunk pre-swizzled lc^(lr&3) so LDS slot c
    // holds global chunk c^(row&3); reads XOR (row&3)<<4 -> identity, 2-way banks.
    const int lr = l >> 2, lc = l & 3;
    const int sch = (lc ^ (lr & 3)) * 8;  // shorts
    const unsigned short* ag[2];
    const unsigned short* bg[2];
#pragma unroll
    for (int j = 0; j < 2; ++j) {
        int ar = row0 + 64 * j + 16 * w + lr;
        if (ar > rowE - 1) ar = rowE - 1;
        ag[j] = A + (size_t)ar * HIDDEN + sch;
        int bc = col0 + 64 * j + 16 * w + lr;
        if (bc > NOUT - 1) bc = NOUT - 1;
        bg[j] = Bm + (size_t)bc * HIDDEN + sch;
    }

    auto STAGE = [&](int buf, int ktile) {
        int kk = ktile * 32;
        char* base = smem + buf * 16384 + w * 1024;
#pragma unroll
        for (int j = 0; j < 2; ++j) gl16(ag[j] + kk, base + j * 4096);
#pragma unroll
        for (int j = 0; j < 2; ++j) gl16(bg[j] + kk, base + 8192 + j * 4096);
        __builtin_amdgcn_sched_barrier(0);  // pin batch boundary for vmcnt counting
    };
    auto COMPUTE = [&](int buf) {
        char* baseA = smem + buf * 16384;
        char* baseB = baseA + 8192;
        bf16x8 af[4], bfm[4];
#pragma unroll
        for (int mi = 0; mi < 4; ++mi) {
            int row = wr + mi * 16 + (l & 15);
            af[mi] = *(const bf16x8*)(baseA + row * 64 +
                        (((l >> 4) << 4) ^ ((row & 3) << 4)));
        }
#pragma unroll
        for (int ni = 0; ni < 4; ++ni) {
            int row = wc + ni * 16 + (l & 15);
            bfm[ni] = *(const bf16x8*)(baseB + row * 64 +
                        (((l >> 4) << 4) ^ ((row & 3) << 4)));
        }
#pragma unroll
        for (int mi = 0; mi < 4; ++mi)
#pragma unroll
            for (int ni = 0; ni < 4; ++ni)
                acc[mi][ni] = mfma16(af[mi], bfm[ni], acc[mi][ni]);
    };

    const int NKT = HIDDEN / 32;  // 160 K-tiles
    STAGE(0, 0); STAGE(1, 1); STAGE(2, 2);
#pragma unroll 1
    for (int kt = 0; kt < NKT - 2; ++kt) {
        asm volatile("s_waitcnt vmcnt(8) lgkmcnt(0)" ::: "memory");
        __builtin_amdgcn_sched_barrier(0);
        __builtin_amdgcn_s_barrier();
        __builtin_amdgcn_sched_barrier(0);
        if (kt + 3 < NKT) STAGE((kt + 3) & 3, kt + 3);
        COMPUTE(kt & 3);
    }
    // kt = NKT-2: only tile NKT-1 may still fly (4 loads)
    asm volatile("s_waitcnt vmcnt(4) lgkmcnt(0)" ::: "memory");
    __builtin_amdgcn_sched_barrier(0);
    __builtin_amdgcn_s_barrier();
    __builtin_amdgcn_sched_barrier(0);
    COMPUTE((NKT - 2) & 3);
    // kt = NKT-1
    asm volatile("s_waitcnt vmcnt(0) lgkmcnt(0)" ::: "memory");
    __builtin_amdgcn_sched_barrier(0);
    __builtin_amdgcn_s_barrier();
    __builtin_amdgcn_sched_barrier(0);
    COMPUTE((NKT - 1) & 3);

    // epilogue: C/D layout col=lane&15, row=(lane>>4)*4+r
#pragma unroll
    for (int mi = 0; mi < 4; ++mi) {
        int rbase = row0 + wr + mi * 16 + ((l >> 4) << 2);
#pragma unroll
        for (int ni = 0; ni < 4; ++ni) {
            int col = col0 + wc + ni * 16 + (l & 15);
            if (col >= NOUT) continue;
#pragma unroll
            for (int rr = 0; rr < 4; ++rr) {
                int row = rbase + rr;
                if (row >= rowE) continue;
                if (SCATTER) {
                    int t = perm[row];
                    outF[(size_t)t * HIDDEN + col] = acc[mi][ni][rr];
                } else {
                    outB[(size_t)row * NOUT + col] = f2bf(acc[mi][ni][rr]);
                }
            }
        }
    }
}

// ---------------- fallback MoE GEMM (fp32 B), round-1 version ----------------
template <int NOUT, bool SCATTER>
__global__ __launch_bounds__(256) void k_moe_gemm(
        const unsigned short* __restrict__ A, const float* __restrict__ B,
        unsigned short* __restrict__ outB, float* __restrict__ outF,
        const int* __restrict__ meta, const int* __restrict__ perm) {
    int mz = blockIdx.z;
    int rowS = meta[mz], rowE = meta[mz + 1];
    int row0 = rowS + blockIdx.y * 128;
    if (row0 >= rowE) return;
    int col0 = blockIdx.x * 128;
    const float* Bm = B + (size_t)mz * NOUT * HIDDEN;

    __shared__ __align__(16) unsigned short As[128 * 64];
    __shared__ __align__(16) unsigned short Bs[128 * 64];
    int tid = threadIdx.x, l = tid & 63, w = tid >> 6;
    int wr = (w >> 1) * 64, wc = (w & 1) * 64;

    f32x4 acc[4][4] = {};
    int sr = tid >> 1, half = tid & 1;
    int arow = row0 + sr;
    if (arow > N_TOK - 1) arow = N_TOK - 1;
    const unsigned short* aptr = A + (size_t)arow * HIDDEN + half * 32;
    int bcol = col0 + sr;
    bool bok = (bcol < NOUT);
    const float* bptr = Bm + (size_t)(bok ? bcol : 0) * HIDDEN + half * 32;

    char* awp[4]; char* bwp[4];
#pragma unroll
    for (int q = 0; q < 4; ++q) {
        int boff = sr * 128 + ((((half * 4 + q) * 16)) ^ ((sr & 7) << 4));
        awp[q] = (char*)As + boff;
        bwp[q] = (char*)Bs + boff;
    }

#pragma unroll 1
    for (int kk = 0; kk < HIDDEN; kk += 64) {
        bf16x8 av[4];
#pragma unroll
        for (int q = 0; q < 4; ++q) av[q] = *(const bf16x8*)(aptr + kk + q * 8);
        bf16x8 bw[4];
#pragma unroll
        for (int q = 0; q < 4; ++q) {
            float4 u, v;
            if (bok) {
                u = ((const float4*)(bptr + kk))[2 * q];
                v = ((const float4*)(bptr + kk))[2 * q + 1];
            } else {
                u = make_float4(0.f, 0.f, 0.f, 0.f);
                v = u;
            }
            bf16x8 pk;
            pk[0] = (short)f2bf(u.x); pk[1] = (short)f2bf(u.y);
            pk[2] = (short)f2bf(u.z); pk[3] = (short)f2bf(u.w);
            pk[4] = (short)f2bf(v.x); pk[5] = (short)f2bf(v.y);
            pk[6] = (short)f2bf(v.z); pk[7] = (short)f2bf(v.w);
            bw[q] = pk;
        }
        __syncthreads();
#pragma unroll
        for (int q = 0; q < 4; ++q) {
            *(bf16x8*)awp[q] = av[q];
            *(bf16x8*)bwp[q] = bw[q];
        }
        __syncthreads();
#pragma unroll
        for (int ks = 0; ks < 2; ++ks) {
            bf16x8 af[4], bfm[4];
#pragma unroll
            for (int mi = 0; mi < 4; ++mi) {
                int row = wr + mi * 16 + (l & 15);
                af[mi] = *(const bf16x8*)((char*)As + row * 128 +
                            ((ks * 64 + (l >> 4) * 16) ^ ((row & 7) << 4)));
            }
#pragma unroll
            for (int ni = 0; ni < 4; ++ni) {
                int row = wc + ni * 16 + (l & 15);
                bfm[ni] = *(const bf16x8*)((char*)Bs + row * 128 +
                            ((ks * 64 + (l >> 4) * 16) ^ ((row & 7) << 4)));
            }
#pragma unroll
            for (int mi = 0; mi < 4; ++mi)
#pragma unroll
                for (int ni = 0; ni < 4; ++ni)
                    acc[mi][ni] = mfma16(af[mi], bfm[ni], acc[mi][ni]);
        }
    }
#pragma unroll
    for (int mi = 0; mi < 4; ++mi) {
        int rbase = row0 + wr + mi * 16 + ((l >> 4) << 2);
#pragma unroll
        for (int ni = 0; ni < 4; ++ni) {
            int col = col0 + wc + ni * 16 + (l & 15);
            if (col >= NOUT) continue;
#pragma unroll
            for (int rr = 0; rr < 4; ++rr) {
                int row = rbase + rr;
                if (row >= rowE) continue;
                if (SCATTER) {
                    int t = perm[row];
                    outF[(size_t)t * HIDDEN + col] = acc[mi][ni][rr];
                } else {
                    outB[(size_t)row * NOUT + col] = f2bf(acc[mi][ni][rr]);
                }
            }
        }
    }
}

// ---------------- qk-norm + rope + gate ----------------
// q is pre-scaled by log2(e)/sqrt(128) so attention uses exp2 directly.
__global__ __launch_bounds__(256) void k_qknorm(const unsigned short* __restrict__ qkv,
        const float* __restrict__ rope, const float* __restrict__ qnw,
        const float* __restrict__ knw, const int* __restrict__ meta,
        const int* __restrict__ perm, unsigned short* __restrict__ qb,
        unsigned short* __restrict__ kb, float* __restrict__ gate) {
    int i = blockIdx.x;
    int m = (i >= meta[1]) + (i >= meta[2]);
    int t = perm[i];
    int tid = threadIdx.x, w = tid >> 6, l = tid & 63;
    const unsigned short* base = qkv + (size_t)i * QKV_OUT;
    const float* rp = rope + (size_t)t * HEAD_DIM;
    const float qscale = 0.08838834764831845f * 1.4426950408889634f;  // log2e/sqrt(128)
    for (int hh = w; hh < 48; hh += 4) {
        bool isq = hh < 40;
        const unsigned short* src = base + (isq ? hh * 128 : Q_SIZE + (hh - 40) * 128);
        float x0 = bf2f(src[2 * l]), x1 = bf2f(src[2 * l + 1]);
        float ss = x0 * x0 + x1 * x1;
        for (int o = 32; o; o >>= 1) ss += __shfl_xor(ss, o);
        float rms = rsqrtf(ss * (1.f / 128.f) + 1e-6f);
        const float* nw = (isq ? qnw : knw) + m * 128;
        float y0 = x0 * rms * (nw[2 * l] + 1.f);
        float y1 = x1 * rms * (nw[2 * l + 1] + 1.f);
        float p0 = __shfl_xor(y0, 32);
        float p1 = __shfl_xor(y1, 32);
        float r0v, r1v;
        if (l < 32) {
            int d = 2 * l;
            r0v = y0 * rp[64 + d] - p0 * rp[d];
            r1v = y1 * rp[64 + d + 1] - p1 * rp[d + 1];
        } else {
            int d = 2 * l - 64;
            r0v = p0 * rp[d] + y0 * rp[64 + d];
            r1v = p1 * rp[d + 1] + y1 * rp[64 + d + 1];
        }
        if (isq) {
            r0v *= qscale; r1v *= qscale;
            unsigned short* dst = qb + (size_t)i * Q_SIZE + hh * 128 + 2 * l;
            dst[0] = f2bf(r0v); dst[1] = f2bf(r1v);
        } else {
            unsigned short* dst = kb + (size_t)i * KV_SIZE + (hh - 40) * 128 + 2 * l;
            dst[0] = f2bf(r0v); dst[1] = f2bf(r1v);
        }
    }
    if (tid < HQ) {
        float g = bf2f(base[Q_SIZE + 2 * KV_SIZE + tid]);
        gate[(size_t)i * HQ + tid] = 1.f / (1.f + expf(-g));
    }
}

// ---------------- transpose V ----------------
__global__ __launch_bounds__(256) void k_vtrans(const unsigned short* __restrict__ qkv,
                                                unsigned short* __restrict__ vT) {
    int t0 = blockIdx.x * 64, db = blockIdx.y * 64, kvh = blockIdx.z;
    __shared__ unsigned short tile[64][68];
    int tid = threadIdx.x;
    int tr = tid >> 2, seg = tid & 3;
    const unsigned short* src = qkv + (size_t)(t0 + tr) * QKV_OUT + Q_SIZE + KV_SIZE +
                                kvh * 128 + db + seg * 16;
    us4* drow = (us4*)&tile[tr][seg * 16];
#pragma unroll
    for (int q = 0; q < 4; ++q) drow[q] = ((const us4*)src)[q];
    __syncthreads();
    int dr = tid >> 2;
    unsigned short* dst = vT + ((size_t)kvh * 128 + db + dr) * N_TOK + t0 + seg * 16;
    unsigned short buf[16];
#pragma unroll
    for (int j = 0; j < 16; ++j) buf[j] = tile[seg * 16 + j][dr];
#pragma unroll
    for (int q = 0; q < 4; ++q) ((us4*)dst)[q] = ((us4*)buf)[q];
}

// ---------------- flash attention, fixed-max softmax ----------------
__global__ __launch_bounds__(256) void k_attn(
        const unsigned short* __restrict__ qb,
        const unsigned short* __restrict__ kb,
        const unsigned short* __restrict__ vT,
        const float* __restrict__ gate,
        unsigned short* __restrict__ og) {
    int qt = blockIdx.x, qh = blockIdx.y, kvh = qh / 5;
    int tid = threadIdx.x, w = tid >> 6, l = tid & 63;
    int q0 = qt * 128 + w * 32;
    __shared__ __align__(16) char smem[49152];
    char* Ks = smem;
    char* Vs = smem + 16384;
    char* Ps = smem + 32768 + w * 4096;

    bf16x8 qf[2][4];
#pragma unroll
    for (int mi = 0; mi < 2; ++mi)
#pragma unroll
        for (int ks = 0; ks < 4; ++ks)
            qf[mi][ks] = *(const bf16x8*)(qb + (size_t)(q0 + mi * 16 + (l & 15)) * Q_SIZE +
                                          qh * 128 + ks * 32 + (l >> 4) * 8);

    f32x4 oacc[2][8] = {};
    f32x4 psum[2] = {};

    int kr = tid >> 2, kseg = tid & 3;
    int vr = tid >> 1, vh2 = tid & 1;

#pragma unroll 1
    for (int kt = 0; kt < 32; ++kt) {
        int t0 = kt * 64;
        bf16x8 kv4[4], vv4[4];
        const unsigned short* ksrc = kb + (size_t)(t0 + kr) * KV_SIZE + kvh * 128 + kseg * 32;
        const unsigned short* vsrc = vT + ((size_t)kvh * 128 + vr) * N_TOK + t0 + vh2 * 32;
#pragma unroll
        for (int q = 0; q < 4; ++q) {
            kv4[q] = *(const bf16x8*)(ksrc + q * 8);
            vv4[q] = *(const bf16x8*)(vsrc + q * 8);
        }
        __syncthreads();
#pragma unroll
        for (int q = 0; q < 4; ++q) {
            *(bf16x8*)(Ks + kr * 256 + ((((kseg * 4 + q) * 16)) ^ ((kr & 7) << 4))) = kv4[q];
            *(bf16x8*)(Vs + vr * 128 + ((((vh2 * 4 + q) * 16)) ^ ((vr & 7) << 4))) = vv4[q];
        }
        __syncthreads();
        // S = Q K^T
        f32x4 s[2][4] = {};
#pragma unroll
        for (int ks = 0; ks < 4; ++ks) {
            bf16x8 kf[4];
#pragma unroll
            for (int ni = 0; ni < 4; ++ni) {
                int row = ni * 16 + (l & 15);
                kf[ni] = *(const bf16x8*)(Ks + row * 256 +
                            ((ks * 64 + (l >> 4) * 16) ^ ((row & 7) << 4)));
            }
#pragma unroll
            for (int mi = 0; mi < 2; ++mi)
#pragma unroll
                for (int ni = 0; ni < 4; ++ni)
                    s[mi][ni] = mfma16(qf[mi][ks], kf[ni], s[mi][ni]);
        }
        // p = exp2(s); per-lane row-sum accumulate; bf16 P to wave-private LDS.
#pragma unroll
        for (int mi = 0; mi < 2; ++mi)
#pragma unroll
            for (int ni = 0; ni < 4; ++ni) {
#pragma unroll
                for (int r = 0; r < 4; ++r) {
                    float p = exp2f(s[mi][ni][r]);
                    psum[mi][r] += p;
                    int qr = mi * 16 + ((l >> 4) << 2) + r;
                    int tcb = (ni * 16 + (l & 15)) * 2;
                    *(unsigned short*)(Ps + qr * 128 +
                        (tcb ^ (((qr >> 2) & 3) << 5))) = f2bf(p);
                }
            }
        // O += P V
#pragma unroll
        for (int ks = 0; ks < 2; ++ks) {
            bf16x8 pa[2];
#pragma unroll
            for (int mi = 0; mi < 2; ++mi) {
                int qr = mi * 16 + (l & 15);
                pa[mi] = *(const bf16x8*)(Ps + qr * 128 +
                            ((ks * 64 + (l >> 4) * 16) ^ (((qr >> 2) & 3) << 5)));
            }
#pragma unroll
            for (int nd = 0; nd < 8; ++nd) {
                int row = nd * 16 + (l & 15);
                bf16x8 vf = *(const bf16x8*)(Vs + row * 128 +
                            ((ks * 64 + (l >> 4) * 16) ^ ((row & 7) << 4)));
#pragma unroll
                for (int mi = 0; mi < 2; ++mi)
                    oacc[mi][nd] = mfma16(pa[mi], vf, oacc[mi][nd]);
            }
        }
    }
    // deferred row-sum reduce: rows live in 16-lane groups (same l>>4)
#pragma unroll
    for (int mi = 0; mi < 2; ++mi)
#pragma unroll
        for (int r = 0; r < 4; ++r) {
            float v = psum[mi][r];
            v += __shfl_xor(v, 1);
            v += __shfl_xor(v, 2);
            v += __shfl_xor(v, 4);
            v += __shfl_xor(v, 8);
            psum[mi][r] = v;
        }
#pragma unroll
    for (int mi = 0; mi < 2; ++mi)
#pragma unroll
        for (int r = 0; r < 4; ++r) {
            int row = q0 + mi * 16 + ((l >> 4) << 2) + r;
            float sc = (1.f / psum[mi][r]) * gate[(size_t)row * HQ + qh];
#pragma unroll
            for (int nd = 0; nd < 8; ++nd)
                og[(size_t)row * Q_SIZE + qh * 128 + nd * 16 + (l & 15)] =
                    f2bf(oacc[mi][nd][r] * sc);
        }
}

extern "C" void kernel_launch(void* const* d_in, const int* in_sizes, int n_in,
                              void* d_out, int out_size, void* d_ws, size_t ws_size,
                              hipStream_t stream) {
    const float* hidden = (const float*)d_in[0];
    const float* rope   = (const float*)d_in[1];
    const float* pnw    = (const float*)d_in[2];
    const float* qkvw   = (const float*)d_in[3];
    const float* qnw    = (const float*)d_in[4];
    const float* knw    = (const float*)d_in[5];
    const float* projw  = (const float*)d_in[6];
    const int*   mids   = (const int*)d_in[7];
    float* out = (float*)d_out;

    char* ws = (char*)d_ws;
    const size_t nqkvw = (size_t)3 * QKV_OUT * HIDDEN;
    const size_t nprojw = (size_t)3 * HIDDEN * Q_SIZE;
    const size_t wbytes = (nqkvw + nprojw) * 2;

    const size_t small_bytes = 16384 +
        (size_t)N_TOK * HIDDEN * 2 +      // h
        (size_t)N_TOK * QKV_OUT * 2 +     // qkv
        (size_t)N_TOK * Q_SIZE * 2 +      // qb
        (size_t)N_TOK * KV_SIZE * 2 +     // kb
        (size_t)N_TOK * KV_SIZE * 2 +     // vT
        (size_t)N_TOK * Q_SIZE * 2 +      // og
        (size_t)N_TOK * HQ * 4;           // gate
    bool use_bf = (ws_size >= wbytes + small_bytes);
    if (!use_bf && ws_size < small_bytes) return;  // loud failure

    unsigned short* wqkv = (unsigned short*)ws;
    unsigned short* wproj = wqkv + nqkvw;
    char* sb = ws + (use_bf ? wbytes : 0);

    int* meta = (int*)sb;
    int* perm = (int*)(sb + 64);
    unsigned short* h   = (unsigned short*)(sb + 16384);
    unsigned short* qkv = h   + (size_t)N_TOK * HIDDEN;
    unsigned short* qb  = qkv + (size_t)N_TOK * QKV_OUT;
    unsigned short* kb  = qb  + (size_t)N_TOK * Q_SIZE;
    unsigned short* vT  = kb  + (size_t)N_TOK * KV_SIZE;
    unsigned short* og  = vT  + (size_t)N_TOK * KV_SIZE;
    float* gate = (float*)(og + (size_t)N_TOK * Q_SIZE);

    k_sort<<<1, 64, 0, stream>>>(mids, meta, perm);
    if (use_bf) {
        k_cvt<<<2048, 256, 0, stream>>>(qkvw, wqkv, (int)(nqkvw / 8));
        k_cvt<<<2048, 256, 0, stream>>>(projw, wproj, (int)(nprojw / 8));
    }
    k_prenorm<<<2048, 256, 0, stream>>>(hidden, pnw, meta, perm, h);
    if (use_bf)
        k_gemm<QKV_OUT, false><<<16 * 57 * 3, 256, 0, stream>>>(
            h, wqkv, qkv, nullptr, meta, perm, 16, 57);
    else
        k_moe_gemm<QKV_OUT, false><<<dim3(57, 16, 3), 256, 0, stream>>>(
            h, qkvw, qkv, nullptr, meta, perm);
    k_qknorm<<<2048, 256, 0, stream>>>(qkv, rope, qnw, knw, meta, perm, qb, kb, gate);
    k_vtrans<<<dim3(32, 2, 8), 256, 0, stream>>>(qkv, vT);
    k_attn<<<dim3(16, 40), 256, 0, stream>>>(qb, kb, vT, gate, og);
    if (use_bf)
        k_gemm<HIDDEN, true><<<16 * 40 * 3, 256, 0, stream>>>(
            og, wproj, nullptr, out, meta, perm, 16, 40);
    else
        k_moe_gemm<HIDDEN, true><<<dim3(40, 16, 3), 256, 0, stream>>>(
            og, projw, nullptr, out, meta, perm);
}

// Round 11
// 919.051 us; speedup vs baseline: 1.0630x; 1.0630x over previous
//
#include <hip/hip_runtime.h>
#include <hip/hip_bf16.h>

#define N_TOK 2048
#define HIDDEN 5120
#define HEAD_DIM 128
#define HQ 40
#define HKV 8
#define QKV_OUT 7208
#define Q_SIZE 5120
#define KV_SIZE 1024

typedef __attribute__((ext_vector_type(8))) short bf16x8;
typedef __attribute__((ext_vector_type(4))) float f32x4;
typedef __attribute__((ext_vector_type(4))) unsigned short us4;

__device__ inline unsigned short f2bf(float f) {
    return __builtin_bit_cast(unsigned short, __float2bfloat16(f));
}
__device__ inline float bf2f(unsigned short s) {
    unsigned u = ((unsigned)s) << 16;
    return __builtin_bit_cast(float, u);
}
__device__ inline f32x4 mfma16(bf16x8 a, bf16x8 b, f32x4 c) {
    return __builtin_amdgcn_mfma_f32_16x16x32_bf16(a, b, c, 0, 0, 0);
}
__device__ inline void gl16(const void* g, void* l) {
    __builtin_amdgcn_global_load_lds((__attribute__((address_space(1))) void*)g,
                                     (__attribute__((address_space(3))) void*)l, 16, 0, 0);
}
__device__ inline void cvt_chunk(const float* __restrict__ src,
                                 unsigned short* __restrict__ dst,
                                 int n8, int i, int stride) {
    for (; i < n8; i += stride) {
        float4 a = ((const float4*)src)[2 * i];
        float4 b = ((const float4*)src)[2 * i + 1];
        bf16x8 o;
        o[0] = (short)f2bf(a.x); o[1] = (short)f2bf(a.y);
        o[2] = (short)f2bf(a.z); o[3] = (short)f2bf(a.w);
        o[4] = (short)f2bf(b.x); o[5] = (short)f2bf(b.y);
        o[6] = (short)f2bf(b.z); o[7] = (short)f2bf(b.w);
        ((bf16x8*)dst)[i] = o;
    }
}

// ---------------- sort tokens by modality (stable) ----------------
__global__ void k_sort(const int* __restrict__ mids_raw, int* __restrict__ meta,
                       int* __restrict__ perm) {
    int l = threadIdx.x;  // 64 threads, 1 wave
    int oddnz = 0;
    for (int c = 0; c < 32; ++c) {
        int idx = c * 64 + l;
        int v = mids_raw[idx];
        if ((idx & 1) && v != 0) oddnz = 1;
    }
    bool is64 = (__ballot(oddnz) == 0ULL);
    int c0 = 0, c1 = 0;
    for (int c = 0; c < 32; ++c) {
        int i = c * 64 + l;
        int m = is64 ? mids_raw[2 * i] : mids_raw[i];
        c0 += (m == 0); c1 += (m == 1);
    }
    for (int o = 32; o; o >>= 1) { c0 += __shfl_xor(c0, o); c1 += __shfl_xor(c1, o); }
    if (l == 0) { meta[0] = 0; meta[1] = c0; meta[2] = c0 + c1; meta[3] = N_TOK; }
    int r0 = 0, r1 = c0, r2 = c0 + c1;
    unsigned long long below = (1ULL << l) - 1ULL;
    for (int c = 0; c < 32; ++c) {
        int i = c * 64 + l;
        int m = is64 ? mids_raw[2 * i] : mids_raw[i];
        unsigned long long b0 = __ballot(m == 0), b1 = __ballot(m == 1), b2 = __ballot(m == 2);
        int pos = (m == 0) ? r0 + __popcll(b0 & below)
                : (m == 1) ? r1 + __popcll(b1 & below)
                           : r2 + __popcll(b2 & below);
        perm[pos] = i;
        r0 += __popcll(b0); r1 += __popcll(b1); r2 += __popcll(b2);
    }
}

// -------- pre-norm (blocks < 2048) + qkv-weight fp32->bf16 cvt (blocks >= 2048) ------
// cvt is pure-HBM and overlaps prenorm's light traffic in the same dispatch.
__global__ __launch_bounds__(256) void k_prenorm_cvt(const float* __restrict__ hidden,
        const float* __restrict__ pnw, const int* __restrict__ meta,
        const int* __restrict__ perm, unsigned short* __restrict__ h,
        const float* __restrict__ csrc, unsigned short* __restrict__ cdst, int n8) {
    int bid = blockIdx.x;
    int tid = threadIdx.x;
    if (bid >= 2048) {
        int b = bid - 2048;
        int stride = (gridDim.x - 2048) * 256;
        cvt_chunk(csrc, cdst, n8, b * 256 + tid, stride);
        return;
    }
    int i = bid;
    int m = (i >= meta[1]) + (i >= meta[2]);
    int t = perm[i];
    const float4* x = (const float4*)(hidden + (size_t)t * HIDDEN);
    const float4* wv = (const float4*)(pnw + (size_t)m * HIDDEN);
    float4 xv[5];
    float ss = 0.f;
#pragma unroll
    for (int j = 0; j < 5; ++j) {
        xv[j] = x[tid + j * 256];
        ss += xv[j].x * xv[j].x + xv[j].y * xv[j].y + xv[j].z * xv[j].z + xv[j].w * xv[j].w;
    }
    for (int o = 32; o; o >>= 1) ss += __shfl_xor(ss, o);
    __shared__ float red[4];
    if ((tid & 63) == 0) red[tid >> 6] = ss;
    __syncthreads();
    float rms = rsqrtf((red[0] + red[1] + red[2] + red[3]) * (1.f / HIDDEN) + 1e-6f);
    us4* dst = (us4*)(h + (size_t)i * HIDDEN);
#pragma unroll
    for (int j = 0; j < 5; ++j) {
        float4 w = wv[tid + j * 256];
        us4 o4;
        o4.x = f2bf(xv[j].x * rms * (w.x + 1.f));
        o4.y = f2bf(xv[j].y * rms * (w.y + 1.f));
        o4.z = f2bf(xv[j].z * rms * (w.z + 1.f));
        o4.w = f2bf(xv[j].w * rms * (w.w + 1.f));
        dst[tid + j * 256] = o4;
    }
}

// ---------------- 128x128 double-buffered MoE GEMM (r7 exact: QKV best) ----------
// STAGE(next) -> COMPUTE(cur) -> vmcnt(0)+barrier. Pre-swizzled source + XOR reads.
template <int NOUT, bool SCATTER>
__global__ __launch_bounds__(256, 2) void k_gemm(
        const unsigned short* __restrict__ A, const unsigned short* __restrict__ Bw,
        unsigned short* __restrict__ outB, float* __restrict__ outF,
        const int* __restrict__ meta, const int* __restrict__ perm,
        int nx, int ny) {
    int nwg = nx * ny * 3;
    int bid = blockIdx.x;
    int xcd = bid & 7, o = bid >> 3;
    int q = nwg >> 3, r = nwg & 7;
    int swz = (xcd < r ? xcd * (q + 1) : r * (q + 1) + (xcd - r) * q) + o;
    int mz = swz / (nx * ny);
    int rest = swz - mz * (nx * ny);
    int ty = rest / nx, tx = rest - ty * nx;

    int rowS = meta[mz], rowE = meta[mz + 1];
    int row0 = rowS + tx * 128;
    if (row0 >= rowE) return;
    int col0 = ty * 128;
    const unsigned short* Bm = Bw + (size_t)mz * NOUT * HIDDEN;

    __shared__ __align__(16) char smem[65536];
    int tid = threadIdx.x, l = tid & 63, w = tid >> 6;
    int wr = (w >> 1) * 64, wc = (w & 1) * 64;

    f32x4 acc[4][4] = {};

    const int lr = l >> 3, lc = l & 7;
    const int sch = (lc ^ lr) * 8;  // shorts
    const unsigned short* ag[4];
    const unsigned short* bg[4];
#pragma unroll
    for (int j = 0; j < 4; ++j) {
        int ar = row0 + 32 * j + 8 * w + lr;
        if (ar > rowE - 1) ar = rowE - 1;
        ag[j] = A + (size_t)ar * HIDDEN + sch;
        int bc = col0 + 32 * j + 8 * w + lr;
        if (bc > NOUT - 1) bc = NOUT - 1;
        bg[j] = Bm + (size_t)bc * HIDDEN + sch;
    }
    char* asw = smem + w * 1024;
    char* bsw = smem + 16384 + w * 1024;

    auto STAGE = [&](int buf, int kk) {
#pragma unroll
        for (int j = 0; j < 4; ++j) {
            gl16(ag[j] + kk, asw + buf * 32768 + j * 4096);
            gl16(bg[j] + kk, bsw + buf * 32768 + j * 4096);
        }
    };
    auto COMPUTE = [&](int buf) {
        char* baseA = smem + buf * 32768;
        char* baseB = baseA + 16384;
#pragma unroll
        for (int ks = 0; ks < 2; ++ks) {
            bf16x8 af[4], bfm[4];
#pragma unroll
            for (int mi = 0; mi < 4; ++mi) {
                int row = wr + mi * 16 + (l & 15);
                af[mi] = *(const bf16x8*)(baseA + row * 128 +
                            ((ks * 64 + (l >> 4) * 16) ^ ((row & 7) << 4)));
            }
#pragma unroll
            for (int ni = 0; ni < 4; ++ni) {
                int row = wc + ni * 16 + (l & 15);
                bfm[ni] = *(const bf16x8*)(baseB + row * 128 +
                            ((ks * 64 + (l >> 4) * 16) ^ ((row & 7) << 4)));
            }
#pragma unroll
            for (int mi = 0; mi < 4; ++mi)
#pragma unroll
                for (int ni = 0; ni < 4; ++ni)
                    acc[mi][ni] = mfma16(af[mi], bfm[ni], acc[mi][ni]);
        }
    };

    STAGE(0, 0);
    asm volatile("s_waitcnt vmcnt(0)" ::: "memory");
    __builtin_amdgcn_sched_barrier(0);
    __builtin_amdgcn_s_barrier();
    __builtin_amdgcn_sched_barrier(0);
    int cur = 0;
#pragma unroll 1
    for (int kt = 0; kt < HIDDEN / 64 - 1; ++kt) {
        STAGE(cur ^ 1, (kt + 1) * 64);
        COMPUTE(cur);
        asm volatile("s_waitcnt vmcnt(0) lgkmcnt(0)" ::: "memory");
        __builtin_amdgcn_sched_barrier(0);
        __builtin_amdgcn_s_barrier();
        __builtin_amdgcn_sched_barrier(0);
        cur ^= 1;
    }
    COMPUTE(cur);

#pragma unroll
    for (int mi = 0; mi < 4; ++mi) {
        int rbase = row0 + wr + mi * 16 + ((l >> 4) << 2);
#pragma unroll
        for (int ni = 0; ni < 4; ++ni) {
            int col = col0 + wc + ni * 16 + (l & 15);
            if (col >= NOUT) continue;
#pragma unroll
            for (int rr = 0; rr < 4; ++rr) {
                int row = rbase + rr;
                if (row >= rowE) continue;
                if (SCATTER) {
                    int t = perm[row];
                    outF[(size_t)t * HIDDEN + col] = acc[mi][ni][rr];
                } else {
                    outB[(size_t)row * NOUT + col] = f2bf(acc[mi][ni][rr]);
                }
            }
        }
    }
}

// ---------------- 128x256 single-buffer MoE GEMM (r6 exact: proj best) ----------
template <int NOUT, bool SCATTER>
__global__ __launch_bounds__(256, 2) void k_gemm2(
        const unsigned short* __restrict__ A, const unsigned short* __restrict__ Bw,
        unsigned short* __restrict__ outB, float* __restrict__ outF,
        const int* __restrict__ meta, const int* __restrict__ perm,
        int nx, int ny) {
    int nwg = nx * ny * 3;
    int bid = blockIdx.x;
    int xcd = bid & 7, o = bid >> 3;
    int q = nwg >> 3, r = nwg & 7;
    int swz = (xcd < r ? xcd * (q + 1) : r * (q + 1) + (xcd - r) * q) + o;
    int mz = swz / (nx * ny);
    int rest = swz - mz * (nx * ny);
    int ty = rest / nx, tx = rest - ty * nx;

    int rowS = meta[mz], rowE = meta[mz + 1];
    int row0 = rowS + tx * 128;
    if (row0 >= rowE) return;
    int col0 = ty * 256;
    const unsigned short* Bm = Bw + (size_t)mz * NOUT * HIDDEN;

    __shared__ __align__(16) unsigned short As[128 * 64];   // 16 KiB
    __shared__ __align__(16) unsigned short Bs[256 * 64];   // 32 KiB
    int tid = threadIdx.x, l = tid & 63, w = tid >> 6;
    int wr = (w >> 1) * 64, wc = (w & 1) * 128;

    f32x4 acc[4][8] = {};

    const int lr = l >> 3, lc = l & 7;
    const int sch = (lc ^ lr) * 8;  // shorts
    const unsigned short* ag[4];
    const unsigned short* bg[8];
#pragma unroll
    for (int j = 0; j < 4; ++j) {
        int ar = row0 + 32 * j + 8 * w + lr;
        if (ar > rowE - 1) ar = rowE - 1;
        ag[j] = A + (size_t)ar * HIDDEN + sch;
    }
#pragma unroll
    for (int j = 0; j < 8; ++j) {
        int bc = col0 + 32 * j + 8 * w + lr;
        if (bc > NOUT - 1) bc = NOUT - 1;
        bg[j] = Bm + (size_t)bc * HIDDEN + sch;
    }
    char* asw = (char*)As + w * 1024;
    char* bsw = (char*)Bs + w * 1024;

#pragma unroll 1
    for (int kk = 0; kk < HIDDEN; kk += 64) {
#pragma unroll
        for (int j = 0; j < 4; ++j) gl16(ag[j] + kk, asw + j * 4096);
#pragma unroll
        for (int j = 0; j < 8; ++j) gl16(bg[j] + kk, bsw + j * 4096);
        __syncthreads();
#pragma unroll
        for (int ks = 0; ks < 2; ++ks) {
            bf16x8 af[4], bfm[8];
#pragma unroll
            for (int mi = 0; mi < 4; ++mi) {
                int row = wr + mi * 16 + (l & 15);
                af[mi] = *(const bf16x8*)((char*)As + row * 128 +
                            ((ks * 64 + (l >> 4) * 16) ^ ((row & 7) << 4)));
            }
#pragma unroll
            for (int ni = 0; ni < 8; ++ni) {
                int row = wc + ni * 16 + (l & 15);
                bfm[ni] = *(const bf16x8*)((char*)Bs + row * 128 +
                            ((ks * 64 + (l >> 4) * 16) ^ ((row & 7) << 4)));
            }
#pragma unroll
            for (int mi = 0; mi < 4; ++mi)
#pragma unroll
                for (int ni = 0; ni < 8; ++ni)
                    acc[mi][ni] = mfma16(af[mi], bfm[ni], acc[mi][ni]);
        }
        __syncthreads();
    }
#pragma unroll
    for (int mi = 0; mi < 4; ++mi) {
        int rbase = row0 + wr + mi * 16 + ((l >> 4) << 2);
#pragma unroll
        for (int ni = 0; ni < 8; ++ni) {
            int col = col0 + wc + ni * 16 + (l & 15);
            if (col >= NOUT) continue;
#pragma unroll
            for (int rr = 0; rr < 4; ++rr) {
                int row = rbase + rr;
                if (row >= rowE) continue;
                if (SCATTER) {
                    int t = perm[row];
                    outF[(size_t)t * HIDDEN + col] = acc[mi][ni][rr];
                } else {
                    outB[(size_t)row * NOUT + col] = f2bf(acc[mi][ni][rr]);
                }
            }
        }
    }
}

// ---------------- fallback MoE GEMM (fp32 B), round-1 version ----------------
template <int NOUT, bool SCATTER>
__global__ __launch_bounds__(256) void k_moe_gemm(
        const unsigned short* __restrict__ A, const float* __restrict__ B,
        unsigned short* __restrict__ outB, float* __restrict__ outF,
        const int* __restrict__ meta, const int* __restrict__ perm) {
    int mz = blockIdx.z;
    int rowS = meta[mz], rowE = meta[mz + 1];
    int row0 = rowS + blockIdx.y * 128;
    if (row0 >= rowE) return;
    int col0 = blockIdx.x * 128;
    const float* Bm = B + (size_t)mz * NOUT * HIDDEN;

    __shared__ __align__(16) unsigned short As[128 * 64];
    __shared__ __align__(16) unsigned short Bs[128 * 64];
    int tid = threadIdx.x, l = tid & 63, w = tid >> 6;
    int wr = (w >> 1) * 64, wc = (w & 1) * 64;

    f32x4 acc[4][4] = {};
    int sr = tid >> 1, half = tid & 1;
    int arow = row0 + sr;
    if (arow > N_TOK - 1) arow = N_TOK - 1;
    const unsigned short* aptr = A + (size_t)arow * HIDDEN + half * 32;
    int bcol = col0 + sr;
    bool bok = (bcol < NOUT);
    const float* bptr = Bm + (size_t)(bok ? bcol : 0) * HIDDEN + half * 32;

    char* awp[4]; char* bwp[4];
#pragma unroll
    for (int q = 0; q < 4; ++q) {
        int boff = sr * 128 + ((((half * 4 + q) * 16)) ^ ((sr & 7) << 4));
        awp[q] = (char*)As + boff;
        bwp[q] = (char*)Bs + boff;
    }

#pragma unroll 1
    for (int kk = 0; kk < HIDDEN; kk += 64) {
        bf16x8 av[4];
#pragma unroll
        for (int q = 0; q < 4; ++q) av[q] = *(const bf16x8*)(aptr + kk + q * 8);
        bf16x8 bw[4];
#pragma unroll
        for (int q = 0; q < 4; ++q) {
            float4 u, v;
            if (bok) {
                u = ((const float4*)(bptr + kk))[2 * q];
                v = ((const float4*)(bptr + kk))[2 * q + 1];
            } else {
                u = make_float4(0.f, 0.f, 0.f, 0.f);
                v = u;
            }
            bf16x8 pk;
            pk[0] = (short)f2bf(u.x); pk[1] = (short)f2bf(u.y);
            pk[2] = (short)f2bf(u.z); pk[3] = (short)f2bf(u.w);
            pk[4] = (short)f2bf(v.x); pk[5] = (short)f2bf(v.y);
            pk[6] = (short)f2bf(v.z); pk[7] = (short)f2bf(v.w);
            bw[q] = pk;
        }
        __syncthreads();
#pragma unroll
        for (int q = 0; q < 4; ++q) {
            *(bf16x8*)awp[q] = av[q];
            *(bf16x8*)bwp[q] = bw[q];
        }
        __syncthreads();
#pragma unroll
        for (int ks = 0; ks < 2; ++ks) {
            bf16x8 af[4], bfm[4];
#pragma unroll
            for (int mi = 0; mi < 4; ++mi) {
                int row = wr + mi * 16 + (l & 15);
                af[mi] = *(const bf16x8*)((char*)As + row * 128 +
                            ((ks * 64 + (l >> 4) * 16) ^ ((row & 7) << 4)));
            }
#pragma unroll
            for (int ni = 0; ni < 4; ++ni) {
                int row = wc + ni * 16 + (l & 15);
                bfm[ni] = *(const bf16x8*)((char*)Bs + row * 128 +
                            ((ks * 64 + (l >> 4) * 16) ^ ((row & 7) << 4)));
            }
#pragma unroll
            for (int mi = 0; mi < 4; ++mi)
#pragma unroll
                for (int ni = 0; ni < 4; ++ni)
                    acc[mi][ni] = mfma16(af[mi], bfm[ni], acc[mi][ni]);
        }
    }
#pragma unroll
    for (int mi = 0; mi < 4; ++mi) {
        int rbase = row0 + wr + mi * 16 + ((l >> 4) << 2);
#pragma unroll
        for (int ni = 0; ni < 4; ++ni) {
            int col = col0 + wc + ni * 16 + (l & 15);
            if (col >= NOUT) continue;
#pragma unroll
            for (int rr = 0; rr < 4; ++rr) {
                int row = rbase + rr;
                if (row >= rowE) continue;
                if (SCATTER) {
                    int t = perm[row];
                    outF[(size_t)t * HIDDEN + col] = acc[mi][ni][rr];
                } else {
                    outB[(size_t)row * NOUT + col] = f2bf(acc[mi][ni][rr]);
                }
            }
        }
    }
}

// ---------------- qk-norm + rope + gate ----------------
__global__ __launch_bounds__(256) void k_qknorm(const unsigned short* __restrict__ qkv,
        const float* __restrict__ rope, const float* __restrict__ qnw,
        const float* __restrict__ knw, const int* __restrict__ meta,
        const int* __restrict__ perm, unsigned short* __restrict__ qb,
        unsigned short* __restrict__ kb, float* __restrict__ gate) {
    int i = blockIdx.x;
    int m = (i >= meta[1]) + (i >= meta[2]);
    int t = perm[i];
    int tid = threadIdx.x, w = tid >> 6, l = tid & 63;
    const unsigned short* base = qkv + (size_t)i * QKV_OUT;
    const float* rp = rope + (size_t)t * HEAD_DIM;
    const float qscale = 0.08838834764831845f * 1.4426950408889634f;  // log2e/sqrt(128)
    for (int hh = w; hh < 48; hh += 4) {
        bool isq = hh < 40;
        const unsigned short* src = base + (isq ? hh * 128 : Q_SIZE + (hh - 40) * 128);
        float x0 = bf2f(src[2 * l]), x1 = bf2f(src[2 * l + 1]);
        float ss = x0 * x0 + x1 * x1;
        for (int o = 32; o; o >>= 1) ss += __shfl_xor(ss, o);
        float rms = rsqrtf(ss * (1.f / 128.f) + 1e-6f);
        const float* nw = (isq ? qnw : knw) + m * 128;
        float y0 = x0 * rms * (nw[2 * l] + 1.f);
        float y1 = x1 * rms * (nw[2 * l + 1] + 1.f);
        float p0 = __shfl_xor(y0, 32);
        float p1 = __shfl_xor(y1, 32);
        float r0v, r1v;
        if (l < 32) {
            int d = 2 * l;
            r0v = y0 * rp[64 + d] - p0 * rp[d];
            r1v = y1 * rp[64 + d + 1] - p1 * rp[d + 1];
        } else {
            int d = 2 * l - 64;
            r0v = p0 * rp[d] + y0 * rp[64 + d];
            r1v = p1 * rp[d + 1] + y1 * rp[64 + d + 1];
        }
        if (isq) {
            r0v *= qscale; r1v *= qscale;
            unsigned short* dst = qb + (size_t)i * Q_SIZE + hh * 128 + 2 * l;
            dst[0] = f2bf(r0v); dst[1] = f2bf(r1v);
        } else {
            unsigned short* dst = kb + (size_t)i * KV_SIZE + (hh - 40) * 128 + 2 * l;
            dst[0] = f2bf(r0v); dst[1] = f2bf(r1v);
        }
    }
    if (tid < HQ) {
        float g = bf2f(base[Q_SIZE + 2 * KV_SIZE + tid]);
        gate[(size_t)i * HQ + tid] = 1.f / (1.f + expf(-g));
    }
}

// ---------------- transpose V ----------------
__global__ __launch_bounds__(256) void k_vtrans(const unsigned short* __restrict__ qkv,
                                                unsigned short* __restrict__ vT) {
    int t0 = blockIdx.x * 64, db = blockIdx.y * 64, kvh = blockIdx.z;
    __shared__ unsigned short tile[64][68];
    int tid = threadIdx.x;
    int tr = tid >> 2, seg = tid & 3;
    const unsigned short* src = qkv + (size_t)(t0 + tr) * QKV_OUT + Q_SIZE + KV_SIZE +
                                kvh * 128 + db + seg * 16;
    us4* drow = (us4*)&tile[tr][seg * 16];
#pragma unroll
    for (int q = 0; q < 4; ++q) drow[q] = ((const us4*)src)[q];
    __syncthreads();
    int dr = tid >> 2;
    unsigned short* dst = vT + ((size_t)kvh * 128 + db + dr) * N_TOK + t0 + seg * 16;
    unsigned short buf[16];
#pragma unroll
    for (int j = 0; j < 16; ++j) buf[j] = tile[seg * 16 + j][dr];
#pragma unroll
    for (int q = 0; q < 4; ++q) ((us4*)dst)[q] = ((us4*)buf)[q];
}

// ------ flash attention (blocks < 640) + proj-weight cvt (blocks >= 640) ------
// cvt is pure-HBM and overlaps attention's compute-bound phase in one dispatch.
__global__ __launch_bounds__(256) void k_attn_cvt(
        const unsigned short* __restrict__ qb,
        const unsigned short* __restrict__ kb,
        const unsigned short* __restrict__ vT,
        const float* __restrict__ gate,
        unsigned short* __restrict__ og,
        const float* __restrict__ csrc, unsigned short* __restrict__ cdst, int n8) {
    int bid = blockIdx.x;
    int tid = threadIdx.x;
    if (bid >= 640) {
        int b = bid - 640;
        int stride = (gridDim.x - 640) * 256;
        cvt_chunk(csrc, cdst, n8, b * 256 + tid, stride);
        return;
    }
    int qt = bid & 15, qh = bid >> 4, kvh = qh / 5;
    int w = tid >> 6, l = tid & 63;
    int q0 = qt * 128 + w * 32;
    __shared__ __align__(16) char smem[49152];
    char* Ks = smem;
    char* Vs = smem + 16384;
    char* Ps = smem + 32768 + w * 4096;

    bf16x8 qf[2][4];
#pragma unroll
    for (int mi = 0; mi < 2; ++mi)
#pragma unroll
        for (int ks = 0; ks < 4; ++ks)
            qf[mi][ks] = *(const bf16x8*)(qb + (size_t)(q0 + mi * 16 + (l & 15)) * Q_SIZE +
                                          qh * 128 + ks * 32 + (l >> 4) * 8);

    f32x4 oacc[2][8] = {};
    f32x4 psum[2] = {};

    int kr = tid >> 2, kseg = tid & 3;
    int vr = tid >> 1, vh2 = tid & 1;

#pragma unroll 1
    for (int kt = 0; kt < 32; ++kt) {
        int t0 = kt * 64;
        bf16x8 kv4[4], vv4[4];
        const unsigned short* ksrc = kb + (size_t)(t0 + kr) * KV_SIZE + kvh * 128 + kseg * 32;
        const unsigned short* vsrc = vT + ((size_t)kvh * 128 + vr) * N_TOK + t0 + vh2 * 32;
#pragma unroll
        for (int q = 0; q < 4; ++q) {
            kv4[q] = *(const bf16x8*)(ksrc + q * 8);
            vv4[q] = *(const bf16x8*)(vsrc + q * 8);
        }
        __syncthreads();
#pragma unroll
        for (int q = 0; q < 4; ++q) {
            *(bf16x8*)(Ks + kr * 256 + ((((kseg * 4 + q) * 16)) ^ ((kr & 7) << 4))) = kv4[q];
            *(bf16x8*)(Vs + vr * 128 + ((((vh2 * 4 + q) * 16)) ^ ((vr & 7) << 4))) = vv4[q];
        }
        __syncthreads();
        // S = Q K^T
        f32x4 s[2][4] = {};
#pragma unroll
        for (int ks = 0; ks < 4; ++ks) {
            bf16x8 kf[4];
#pragma unroll
            for (int ni = 0; ni < 4; ++ni) {
                int row = ni * 16 + (l & 15);
                kf[ni] = *(const bf16x8*)(Ks + row * 256 +
                            ((ks * 64 + (l >> 4) * 16) ^ ((row & 7) << 4)));
            }
#pragma unroll
            for (int mi = 0; mi < 2; ++mi)
#pragma unroll
                for (int ni = 0; ni < 4; ++ni)
                    s[mi][ni] = mfma16(qf[mi][ks], kf[ni], s[mi][ni]);
        }
        // p = exp2(s); per-lane row-sum accumulate; bf16 P to wave-private LDS.
#pragma unroll
        for (int mi = 0; mi < 2; ++mi)
#pragma unroll
            for (int ni = 0; ni < 4; ++ni) {
#pragma unroll
                for (int r = 0; r < 4; ++r) {
                    float p = exp2f(s[mi][ni][r]);
                    psum[mi][r] += p;
                    int qr = mi * 16 + ((l >> 4) << 2) + r;
                    int tcb = (ni * 16 + (l & 15)) * 2;
                    *(unsigned short*)(Ps + qr * 128 +
                        (tcb ^ (((qr >> 2) & 3) << 5))) = f2bf(p);
                }
            }
        // O += P V
#pragma unroll
        for (int ks = 0; ks < 2; ++ks) {
            bf16x8 pa[2];
#pragma unroll
            for (int mi = 0; mi < 2; ++mi) {
                int qr = mi * 16 + (l & 15);
                pa[mi] = *(const bf16x8*)(Ps + qr * 128 +
                            ((ks * 64 + (l >> 4) * 16) ^ (((qr >> 2) & 3) << 5)));
            }
#pragma unroll
            for (int nd = 0; nd < 8; ++nd) {
                int row = nd * 16 + (l & 15);
                bf16x8 vf = *(const bf16x8*)(Vs + row * 128 +
                            ((ks * 64 + (l >> 4) * 16) ^ ((row & 7) << 4)));
#pragma unroll
                for (int mi = 0; mi < 2; ++mi)
                    oacc[mi][nd] = mfma16(pa[mi], vf, oacc[mi][nd]);
            }
        }
    }
    // deferred row-sum reduce: rows live in 16-lane groups (same l>>4)
#pragma unroll
    for (int mi = 0; mi < 2; ++mi)
#pragma unroll
        for (int r = 0; r < 4; ++r) {
            float v = psum[mi][r];
            v += __shfl_xor(v, 1);
            v += __shfl_xor(v, 2);
            v += __shfl_xor(v, 4);
            v += __shfl_xor(v, 8);
            psum[mi][r] = v;
        }
#pragma unroll
    for (int mi = 0; mi < 2; ++mi)
#pragma unroll
        for (int r = 0; r < 4; ++r) {
            int row = q0 + mi * 16 + ((l >> 4) << 2) + r;
            float sc = (1.f / psum[mi][r]) * gate[(size_t)row * HQ + qh];
#pragma unroll
            for (int nd = 0; nd < 8; ++nd)
                og[(size_t)row * Q_SIZE + qh * 128 + nd * 16 + (l & 15)] =
                    f2bf(oacc[mi][nd][r] * sc);
        }
}

extern "C" void kernel_launch(void* const* d_in, const int* in_sizes, int n_in,
                              void* d_out, int out_size, void* d_ws, size_t ws_size,
                              hipStream_t stream) {
    const float* hidden = (const float*)d_in[0];
    const float* rope   = (const float*)d_in[1];
    const float* pnw    = (const float*)d_in[2];
    const float* qkvw   = (const float*)d_in[3];
    const float* qnw    = (const float*)d_in[4];
    const float* knw    = (const float*)d_in[5];
    const float* projw  = (const float*)d_in[6];
    const int*   mids   = (const int*)d_in[7];
    float* out = (float*)d_out;

    char* ws = (char*)d_ws;
    const size_t nqkvw = (size_t)3 * QKV_OUT * HIDDEN;
    const size_t nprojw = (size_t)3 * HIDDEN * Q_SIZE;
    const size_t wbytes = (nqkvw + nprojw) * 2;

    const size_t small_bytes = 16384 +
        (size_t)N_TOK * HIDDEN * 2 +      // h
        (size_t)N_TOK * QKV_OUT * 2 +     // qkv
        (size_t)N_TOK * Q_SIZE * 2 +      // qb
        (size_t)N_TOK * KV_SIZE * 2 +     // kb
        (size_t)N_TOK * KV_SIZE * 2 +     // vT
        (size_t)N_TOK * Q_SIZE * 2 +      // og
        (size_t)N_TOK * HQ * 4;           // gate
    bool use_bf = (ws_size >= wbytes + small_bytes);
    if (!use_bf && ws_size < small_bytes) return;  // loud failure

    unsigned short* wqkv = (unsigned short*)ws;
    unsigned short* wproj = wqkv + nqkvw;
    char* sb = ws + (use_bf ? wbytes : 0);

    int* meta = (int*)sb;
    int* perm = (int*)(sb + 64);
    unsigned short* h   = (unsigned short*)(sb + 16384);
    unsigned short* qkv = h   + (size_t)N_TOK * HIDDEN;
    unsigned short* qb  = qkv + (size_t)N_TOK * QKV_OUT;
    unsigned short* kb  = qb  + (size_t)N_TOK * Q_SIZE;
    unsigned short* vT  = kb  + (size_t)N_TOK * KV_SIZE;
    unsigned short* og  = vT  + (size_t)N_TOK * KV_SIZE;
    float* gate = (float*)(og + (size_t)N_TOK * Q_SIZE);

    k_sort<<<1, 64, 0, stream>>>(mids, meta, perm);
    if (use_bf) {
        // prenorm + qkv-weight cvt overlapped in one dispatch
        k_prenorm_cvt<<<2048 + 1024, 256, 0, stream>>>(
            hidden, pnw, meta, perm, h, qkvw, wqkv, (int)(nqkvw / 8));
        k_gemm<QKV_OUT, false><<<16 * 57 * 3, 256, 0, stream>>>(
            h, wqkv, qkv, nullptr, meta, perm, 16, 57);
        k_qknorm<<<2048, 256, 0, stream>>>(qkv, rope, qnw, knw, meta, perm, qb, kb, gate);
        k_vtrans<<<dim3(32, 2, 8), 256, 0, stream>>>(qkv, vT);
        // attention + proj-weight cvt overlapped in one dispatch
        k_attn_cvt<<<640 + 1024, 256, 0, stream>>>(
            qb, kb, vT, gate, og, projw, wproj, (int)(nprojw / 8));
        k_gemm2<HIDDEN, true><<<16 * 20 * 3, 256, 0, stream>>>(
            og, wproj, nullptr, out, meta, perm, 16, 20);
    } else {
        k_prenorm_cvt<<<2048, 256, 0, stream>>>(
            hidden, pnw, meta, perm, h, nullptr, nullptr, 0);
        k_moe_gemm<QKV_OUT, false><<<dim3(57, 16, 3), 256, 0, stream>>>(
            h, qkvw, qkv, nullptr, meta, perm);
        k_qknorm<<<2048, 256, 0, stream>>>(qkv, rope, qnw, knw, meta, perm, qb, kb, gate);
        k_vtrans<<<dim3(32, 2, 8), 256, 0, stream>>>(qkv, vT);
        k_attn_cvt<<<640, 256, 0, stream>>>(
            qb, kb, vT, gate, og, nullptr, nullptr, 0);
        k_moe_gemm<HIDDEN, true><<<dim3(40, 16, 3), 256, 0, stream>>>(
            og, projw, nullptr, out, meta, perm);
    }
}

// Round 12
// 873.348 us; speedup vs baseline: 1.1186x; 1.0523x over previous
//
#include <hip/hip_runtime.h>
#include <hip/hip_bf16.h>

#define N_TOK 2048
#define HIDDEN 5120
#define HEAD_DIM 128
#define HQ 40
#define HKV 8
#define QKV_OUT 7208
#define Q_SIZE 5120
#define KV_SIZE 1024

typedef __attribute__((ext_vector_type(8))) short bf16x8;
typedef __attribute__((ext_vector_type(4))) float f32x4;
typedef __attribute__((ext_vector_type(4))) unsigned short us4;

__device__ inline unsigned short f2bf(float f) {
    return __builtin_bit_cast(unsigned short, __float2bfloat16(f));
}
__device__ inline float bf2f(unsigned short s) {
    unsigned u = ((unsigned)s) << 16;
    return __builtin_bit_cast(float, u);
}
__device__ inline f32x4 mfma16(bf16x8 a, bf16x8 b, f32x4 c) {
    return __builtin_amdgcn_mfma_f32_16x16x32_bf16(a, b, c, 0, 0, 0);
}
__device__ inline void gl16(const void* g, void* l) {
    __builtin_amdgcn_global_load_lds((__attribute__((address_space(1))) void*)g,
                                     (__attribute__((address_space(3))) void*)l, 16, 0, 0);
}
__device__ inline void cvt_chunk(const float* __restrict__ src,
                                 unsigned short* __restrict__ dst,
                                 int n8, int i, int stride) {
    for (; i < n8; i += stride) {
        float4 a = ((const float4*)src)[2 * i];
        float4 b = ((const float4*)src)[2 * i + 1];
        bf16x8 o;
        o[0] = (short)f2bf(a.x); o[1] = (short)f2bf(a.y);
        o[2] = (short)f2bf(a.z); o[3] = (short)f2bf(a.w);
        o[4] = (short)f2bf(b.x); o[5] = (short)f2bf(b.y);
        o[6] = (short)f2bf(b.z); o[7] = (short)f2bf(b.w);
        ((bf16x8*)dst)[i] = o;
    }
}

// ---------------- sort tokens by modality (stable) ----------------
__global__ void k_sort(const int* __restrict__ mids_raw, int* __restrict__ meta,
                       int* __restrict__ perm) {
    int l = threadIdx.x;  // 64 threads, 1 wave
    int oddnz = 0;
    for (int c = 0; c < 32; ++c) {
        int idx = c * 64 + l;
        int v = mids_raw[idx];
        if ((idx & 1) && v != 0) oddnz = 1;
    }
    bool is64 = (__ballot(oddnz) == 0ULL);
    int c0 = 0, c1 = 0;
    for (int c = 0; c < 32; ++c) {
        int i = c * 64 + l;
        int m = is64 ? mids_raw[2 * i] : mids_raw[i];
        c0 += (m == 0); c1 += (m == 1);
    }
    for (int o = 32; o; o >>= 1) { c0 += __shfl_xor(c0, o); c1 += __shfl_xor(c1, o); }
    if (l == 0) { meta[0] = 0; meta[1] = c0; meta[2] = c0 + c1; meta[3] = N_TOK; }
    int r0 = 0, r1 = c0, r2 = c0 + c1;
    unsigned long long below = (1ULL << l) - 1ULL;
    for (int c = 0; c < 32; ++c) {
        int i = c * 64 + l;
        int m = is64 ? mids_raw[2 * i] : mids_raw[i];
        unsigned long long b0 = __ballot(m == 0), b1 = __ballot(m == 1), b2 = __ballot(m == 2);
        int pos = (m == 0) ? r0 + __popcll(b0 & below)
                : (m == 1) ? r1 + __popcll(b1 & below)
                           : r2 + __popcll(b2 & below);
        perm[pos] = i;
        r0 += __popcll(b0); r1 += __popcll(b1); r2 += __popcll(b2);
    }
}

// -------- pre-norm (blocks < 2048) + qkv-weight fp32->bf16 cvt (blocks >= 2048) ------
__global__ __launch_bounds__(256) void k_prenorm_cvt(const float* __restrict__ hidden,
        const float* __restrict__ pnw, const int* __restrict__ meta,
        const int* __restrict__ perm, unsigned short* __restrict__ h,
        const float* __restrict__ csrc, unsigned short* __restrict__ cdst, int n8) {
    int bid = blockIdx.x;
    int tid = threadIdx.x;
    if (bid >= 2048) {
        int b = bid - 2048;
        int stride = (gridDim.x - 2048) * 256;
        cvt_chunk(csrc, cdst, n8, b * 256 + tid, stride);
        return;
    }
    int i = bid;
    int m = (i >= meta[1]) + (i >= meta[2]);
    int t = perm[i];
    const float4* x = (const float4*)(hidden + (size_t)t * HIDDEN);
    const float4* wv = (const float4*)(pnw + (size_t)m * HIDDEN);
    float4 xv[5];
    float ss = 0.f;
#pragma unroll
    for (int j = 0; j < 5; ++j) {
        xv[j] = x[tid + j * 256];
        ss += xv[j].x * xv[j].x + xv[j].y * xv[j].y + xv[j].z * xv[j].z + xv[j].w * xv[j].w;
    }
    for (int o = 32; o; o >>= 1) ss += __shfl_xor(ss, o);
    __shared__ float red[4];
    if ((tid & 63) == 0) red[tid >> 6] = ss;
    __syncthreads();
    float rms = rsqrtf((red[0] + red[1] + red[2] + red[3]) * (1.f / HIDDEN) + 1e-6f);
    us4* dst = (us4*)(h + (size_t)i * HIDDEN);
#pragma unroll
    for (int j = 0; j < 5; ++j) {
        float4 w = wv[tid + j * 256];
        us4 o4;
        o4.x = f2bf(xv[j].x * rms * (w.x + 1.f));
        o4.y = f2bf(xv[j].y * rms * (w.y + 1.f));
        o4.z = f2bf(xv[j].z * rms * (w.z + 1.f));
        o4.w = f2bf(xv[j].w * rms * (w.w + 1.f));
        dst[tid + j * 256] = o4;
    }
}

// ---- 128x128 dbuf MoE GEMM (r7 QKV best) + proj-weight cvt tail blocks ----
// GEMM is compute-bound at ~730 GB/s HBM -> the cvt stream rides the idle pipe.
template <int NOUT, bool SCATTER>
__global__ __launch_bounds__(256, 2) void k_gemm(
        const unsigned short* __restrict__ A, const unsigned short* __restrict__ Bw,
        unsigned short* __restrict__ outB, float* __restrict__ outF,
        const int* __restrict__ meta, const int* __restrict__ perm,
        int nx, int ny,
        const float* __restrict__ csrc, unsigned short* __restrict__ cdst, int n8) {
    int nwg = nx * ny * 3;
    int bid = blockIdx.x;
    if (bid >= nwg) {
        int b = bid - nwg;
        int stride = (gridDim.x - nwg) * 256;
        cvt_chunk(csrc, cdst, n8, b * 256 + (int)threadIdx.x, stride);
        return;
    }
    int xcd = bid & 7, o = bid >> 3;
    int q = nwg >> 3, r = nwg & 7;
    int swz = (xcd < r ? xcd * (q + 1) : r * (q + 1) + (xcd - r) * q) + o;
    int mz = swz / (nx * ny);
    int rest = swz - mz * (nx * ny);
    int ty = rest / nx, tx = rest - ty * nx;

    int rowS = meta[mz], rowE = meta[mz + 1];
    int row0 = rowS + tx * 128;
    if (row0 >= rowE) return;
    int col0 = ty * 128;
    const unsigned short* Bm = Bw + (size_t)mz * NOUT * HIDDEN;

    __shared__ __align__(16) char smem[65536];
    int tid = threadIdx.x, l = tid & 63, w = tid >> 6;
    int wr = (w >> 1) * 64, wc = (w & 1) * 64;

    f32x4 acc[4][4] = {};

    const int lr = l >> 3, lc = l & 7;
    const int sch = (lc ^ lr) * 8;  // shorts
    const unsigned short* ag[4];
    const unsigned short* bg[4];
#pragma unroll
    for (int j = 0; j < 4; ++j) {
        int ar = row0 + 32 * j + 8 * w + lr;
        if (ar > rowE - 1) ar = rowE - 1;
        ag[j] = A + (size_t)ar * HIDDEN + sch;
        int bc = col0 + 32 * j + 8 * w + lr;
        if (bc > NOUT - 1) bc = NOUT - 1;
        bg[j] = Bm + (size_t)bc * HIDDEN + sch;
    }
    char* asw = smem + w * 1024;
    char* bsw = smem + 16384 + w * 1024;

    auto STAGE = [&](int buf, int kk) {
#pragma unroll
        for (int j = 0; j < 4; ++j) {
            gl16(ag[j] + kk, asw + buf * 32768 + j * 4096);
            gl16(bg[j] + kk, bsw + buf * 32768 + j * 4096);
        }
    };
    auto COMPUTE = [&](int buf) {
        char* baseA = smem + buf * 32768;
        char* baseB = baseA + 16384;
#pragma unroll
        for (int ks = 0; ks < 2; ++ks) {
            bf16x8 af[4], bfm[4];
#pragma unroll
            for (int mi = 0; mi < 4; ++mi) {
                int row = wr + mi * 16 + (l & 15);
                af[mi] = *(const bf16x8*)(baseA + row * 128 +
                            ((ks * 64 + (l >> 4) * 16) ^ ((row & 7) << 4)));
            }
#pragma unroll
            for (int ni = 0; ni < 4; ++ni) {
                int row = wc + ni * 16 + (l & 15);
                bfm[ni] = *(const bf16x8*)(baseB + row * 128 +
                            ((ks * 64 + (l >> 4) * 16) ^ ((row & 7) << 4)));
            }
#pragma unroll
            for (int mi = 0; mi < 4; ++mi)
#pragma unroll
                for (int ni = 0; ni < 4; ++ni)
                    acc[mi][ni] = mfma16(af[mi], bfm[ni], acc[mi][ni]);
        }
    };

    STAGE(0, 0);
    asm volatile("s_waitcnt vmcnt(0)" ::: "memory");
    __builtin_amdgcn_sched_barrier(0);
    __builtin_amdgcn_s_barrier();
    __builtin_amdgcn_sched_barrier(0);
    int cur = 0;
#pragma unroll 1
    for (int kt = 0; kt < HIDDEN / 64 - 1; ++kt) {
        STAGE(cur ^ 1, (kt + 1) * 64);
        COMPUTE(cur);
        asm volatile("s_waitcnt vmcnt(0) lgkmcnt(0)" ::: "memory");
        __builtin_amdgcn_sched_barrier(0);
        __builtin_amdgcn_s_barrier();
        __builtin_amdgcn_sched_barrier(0);
        cur ^= 1;
    }
    COMPUTE(cur);

#pragma unroll
    for (int mi = 0; mi < 4; ++mi) {
        int rbase = row0 + wr + mi * 16 + ((l >> 4) << 2);
#pragma unroll
        for (int ni = 0; ni < 4; ++ni) {
            int col = col0 + wc + ni * 16 + (l & 15);
            if (col >= NOUT) continue;
#pragma unroll
            for (int rr = 0; rr < 4; ++rr) {
                int row = rbase + rr;
                if (row >= rowE) continue;
                if (SCATTER) {
                    int t = perm[row];
                    outF[(size_t)t * HIDDEN + col] = acc[mi][ni][rr];
                } else {
                    outB[(size_t)row * NOUT + col] = f2bf(acc[mi][ni][rr]);
                }
            }
        }
    }
}

// ---------------- 128x256 single-buffer MoE GEMM (r6 exact: proj best) ----------
template <int NOUT, bool SCATTER>
__global__ __launch_bounds__(256, 2) void k_gemm2(
        const unsigned short* __restrict__ A, const unsigned short* __restrict__ Bw,
        unsigned short* __restrict__ outB, float* __restrict__ outF,
        const int* __restrict__ meta, const int* __restrict__ perm,
        int nx, int ny) {
    int nwg = nx * ny * 3;
    int bid = blockIdx.x;
    int xcd = bid & 7, o = bid >> 3;
    int q = nwg >> 3, r = nwg & 7;
    int swz = (xcd < r ? xcd * (q + 1) : r * (q + 1) + (xcd - r) * q) + o;
    int mz = swz / (nx * ny);
    int rest = swz - mz * (nx * ny);
    int ty = rest / nx, tx = rest - ty * nx;

    int rowS = meta[mz], rowE = meta[mz + 1];
    int row0 = rowS + tx * 128;
    if (row0 >= rowE) return;
    int col0 = ty * 256;
    const unsigned short* Bm = Bw + (size_t)mz * NOUT * HIDDEN;

    __shared__ __align__(16) unsigned short As[128 * 64];   // 16 KiB
    __shared__ __align__(16) unsigned short Bs[256 * 64];   // 32 KiB
    int tid = threadIdx.x, l = tid & 63, w = tid >> 6;
    int wr = (w >> 1) * 64, wc = (w & 1) * 128;

    f32x4 acc[4][8] = {};

    const int lr = l >> 3, lc = l & 7;
    const int sch = (lc ^ lr) * 8;  // shorts
    const unsigned short* ag[4];
    const unsigned short* bg[8];
#pragma unroll
    for (int j = 0; j < 4; ++j) {
        int ar = row0 + 32 * j + 8 * w + lr;
        if (ar > rowE - 1) ar = rowE - 1;
        ag[j] = A + (size_t)ar * HIDDEN + sch;
    }
#pragma unroll
    for (int j = 0; j < 8; ++j) {
        int bc = col0 + 32 * j + 8 * w + lr;
        if (bc > NOUT - 1) bc = NOUT - 1;
        bg[j] = Bm + (size_t)bc * HIDDEN + sch;
    }
    char* asw = (char*)As + w * 1024;
    char* bsw = (char*)Bs + w * 1024;

#pragma unroll 1
    for (int kk = 0; kk < HIDDEN; kk += 64) {
#pragma unroll
        for (int j = 0; j < 4; ++j) gl16(ag[j] + kk, asw + j * 4096);
#pragma unroll
        for (int j = 0; j < 8; ++j) gl16(bg[j] + kk, bsw + j * 4096);
        __syncthreads();
#pragma unroll
        for (int ks = 0; ks < 2; ++ks) {
            bf16x8 af[4], bfm[8];
#pragma unroll
            for (int mi = 0; mi < 4; ++mi) {
                int row = wr + mi * 16 + (l & 15);
                af[mi] = *(const bf16x8*)((char*)As + row * 128 +
                            ((ks * 64 + (l >> 4) * 16) ^ ((row & 7) << 4)));
            }
#pragma unroll
            for (int ni = 0; ni < 8; ++ni) {
                int row = wc + ni * 16 + (l & 15);
                bfm[ni] = *(const bf16x8*)((char*)Bs + row * 128 +
                            ((ks * 64 + (l >> 4) * 16) ^ ((row & 7) << 4)));
            }
#pragma unroll
            for (int mi = 0; mi < 4; ++mi)
#pragma unroll
                for (int ni = 0; ni < 8; ++ni)
                    acc[mi][ni] = mfma16(af[mi], bfm[ni], acc[mi][ni]);
        }
        __syncthreads();
    }
#pragma unroll
    for (int mi = 0; mi < 4; ++mi) {
        int rbase = row0 + wr + mi * 16 + ((l >> 4) << 2);
#pragma unroll
        for (int ni = 0; ni < 8; ++ni) {
            int col = col0 + wc + ni * 16 + (l & 15);
            if (col >= NOUT) continue;
#pragma unroll
            for (int rr = 0; rr < 4; ++rr) {
                int row = rbase + rr;
                if (row >= rowE) continue;
                if (SCATTER) {
                    int t = perm[row];
                    outF[(size_t)t * HIDDEN + col] = acc[mi][ni][rr];
                } else {
                    outB[(size_t)row * NOUT + col] = f2bf(acc[mi][ni][rr]);
                }
            }
        }
    }
}

// ---------------- fallback MoE GEMM (fp32 B), round-1 version ----------------
template <int NOUT, bool SCATTER>
__global__ __launch_bounds__(256) void k_moe_gemm(
        const unsigned short* __restrict__ A, const float* __restrict__ B,
        unsigned short* __restrict__ outB, float* __restrict__ outF,
        const int* __restrict__ meta, const int* __restrict__ perm) {
    int mz = blockIdx.z;
    int rowS = meta[mz], rowE = meta[mz + 1];
    int row0 = rowS + blockIdx.y * 128;
    if (row0 >= rowE) return;
    int col0 = blockIdx.x * 128;
    const float* Bm = B + (size_t)mz * NOUT * HIDDEN;

    __shared__ __align__(16) unsigned short As[128 * 64];
    __shared__ __align__(16) unsigned short Bs[128 * 64];
    int tid = threadIdx.x, l = tid & 63, w = tid >> 6;
    int wr = (w >> 1) * 64, wc = (w & 1) * 64;

    f32x4 acc[4][4] = {};
    int sr = tid >> 1, half = tid & 1;
    int arow = row0 + sr;
    if (arow > N_TOK - 1) arow = N_TOK - 1;
    const unsigned short* aptr = A + (size_t)arow * HIDDEN + half * 32;
    int bcol = col0 + sr;
    bool bok = (bcol < NOUT);
    const float* bptr = Bm + (size_t)(bok ? bcol : 0) * HIDDEN + half * 32;

    char* awp[4]; char* bwp[4];
#pragma unroll
    for (int q = 0; q < 4; ++q) {
        int boff = sr * 128 + ((((half * 4 + q) * 16)) ^ ((sr & 7) << 4));
        awp[q] = (char*)As + boff;
        bwp[q] = (char*)Bs + boff;
    }

#pragma unroll 1
    for (int kk = 0; kk < HIDDEN; kk += 64) {
        bf16x8 av[4];
#pragma unroll
        for (int q = 0; q < 4; ++q) av[q] = *(const bf16x8*)(aptr + kk + q * 8);
        bf16x8 bw[4];
#pragma unroll
        for (int q = 0; q < 4; ++q) {
            float4 u, v;
            if (bok) {
                u = ((const float4*)(bptr + kk))[2 * q];
                v = ((const float4*)(bptr + kk))[2 * q + 1];
            } else {
                u = make_float4(0.f, 0.f, 0.f, 0.f);
                v = u;
            }
            bf16x8 pk;
            pk[0] = (short)f2bf(u.x); pk[1] = (short)f2bf(u.y);
            pk[2] = (short)f2bf(u.z); pk[3] = (short)f2bf(u.w);
            pk[4] = (short)f2bf(v.x); pk[5] = (short)f2bf(v.y);
            pk[6] = (short)f2bf(v.z); pk[7] = (short)f2bf(v.w);
            bw[q] = pk;
        }
        __syncthreads();
#pragma unroll
        for (int q = 0; q < 4; ++q) {
            *(bf16x8*)awp[q] = av[q];
            *(bf16x8*)bwp[q] = bw[q];
        }
        __syncthreads();
#pragma unroll
        for (int ks = 0; ks < 2; ++ks) {
            bf16x8 af[4], bfm[4];
#pragma unroll
            for (int mi = 0; mi < 4; ++mi) {
                int row = wr + mi * 16 + (l & 15);
                af[mi] = *(const bf16x8*)((char*)As + row * 128 +
                            ((ks * 64 + (l >> 4) * 16) ^ ((row & 7) << 4)));
            }
#pragma unroll
            for (int ni = 0; ni < 4; ++ni) {
                int row = wc + ni * 16 + (l & 15);
                bfm[ni] = *(const bf16x8*)((char*)Bs + row * 128 +
                            ((ks * 64 + (l >> 4) * 16) ^ ((row & 7) << 4)));
            }
#pragma unroll
            for (int mi = 0; mi < 4; ++mi)
#pragma unroll
                for (int ni = 0; ni < 4; ++ni)
                    acc[mi][ni] = mfma16(af[mi], bfm[ni], acc[mi][ni]);
        }
    }
#pragma unroll
    for (int mi = 0; mi < 4; ++mi) {
        int rbase = row0 + wr + mi * 16 + ((l >> 4) << 2);
#pragma unroll
        for (int ni = 0; ni < 4; ++ni) {
            int col = col0 + wc + ni * 16 + (l & 15);
            if (col >= NOUT) continue;
#pragma unroll
            for (int rr = 0; rr < 4; ++rr) {
                int row = rbase + rr;
                if (row >= rowE) continue;
                if (SCATTER) {
                    int t = perm[row];
                    outF[(size_t)t * HIDDEN + col] = acc[mi][ni][rr];
                } else {
                    outB[(size_t)row * NOUT + col] = f2bf(acc[mi][ni][rr]);
                }
            }
        }
    }
}

// ---------------- qk-norm + rope + gate ----------------
__global__ __launch_bounds__(256) void k_qknorm(const unsigned short* __restrict__ qkv,
        const float* __restrict__ rope, const float* __restrict__ qnw,
        const float* __restrict__ knw, const int* __restrict__ meta,
        const int* __restrict__ perm, unsigned short* __restrict__ qb,
        unsigned short* __restrict__ kb, float* __restrict__ gate) {
    int i = blockIdx.x;
    int m = (i >= meta[1]) + (i >= meta[2]);
    int t = perm[i];
    int tid = threadIdx.x, w = tid >> 6, l = tid & 63;
    const unsigned short* base = qkv + (size_t)i * QKV_OUT;
    const float* rp = rope + (size_t)t * HEAD_DIM;
    const float qscale = 0.08838834764831845f * 1.4426950408889634f;  // log2e/sqrt(128)
    for (int hh = w; hh < 48; hh += 4) {
        bool isq = hh < 40;
        const unsigned short* src = base + (isq ? hh * 128 : Q_SIZE + (hh - 40) * 128);
        float x0 = bf2f(src[2 * l]), x1 = bf2f(src[2 * l + 1]);
        float ss = x0 * x0 + x1 * x1;
        for (int o = 32; o; o >>= 1) ss += __shfl_xor(ss, o);
        float rms = rsqrtf(ss * (1.f / 128.f) + 1e-6f);
        const float* nw = (isq ? qnw : knw) + m * 128;
        float y0 = x0 * rms * (nw[2 * l] + 1.f);
        float y1 = x1 * rms * (nw[2 * l + 1] + 1.f);
        float p0 = __shfl_xor(y0, 32);
        float p1 = __shfl_xor(y1, 32);
        float r0v, r1v;
        if (l < 32) {
            int d = 2 * l;
            r0v = y0 * rp[64 + d] - p0 * rp[d];
            r1v = y1 * rp[64 + d + 1] - p1 * rp[d + 1];
        } else {
            int d = 2 * l - 64;
            r0v = p0 * rp[d] + y0 * rp[64 + d];
            r1v = p1 * rp[d + 1] + y1 * rp[64 + d + 1];
        }
        if (isq) {
            r0v *= qscale; r1v *= qscale;
            unsigned short* dst = qb + (size_t)i * Q_SIZE + hh * 128 + 2 * l;
            dst[0] = f2bf(r0v); dst[1] = f2bf(r1v);
        } else {
            unsigned short* dst = kb + (size_t)i * KV_SIZE + (hh - 40) * 128 + 2 * l;
            dst[0] = f2bf(r0v); dst[1] = f2bf(r1v);
        }
    }
    if (tid < HQ) {
        float g = bf2f(base[Q_SIZE + 2 * KV_SIZE + tid]);
        gate[(size_t)i * HQ + tid] = 1.f / (1.f + expf(-g));
    }
}

// ---------------- transpose V ----------------
__global__ __launch_bounds__(256) void k_vtrans(const unsigned short* __restrict__ qkv,
                                                unsigned short* __restrict__ vT) {
    int t0 = blockIdx.x * 64, db = blockIdx.y * 64, kvh = blockIdx.z;
    __shared__ unsigned short tile[64][68];
    int tid = threadIdx.x;
    int tr = tid >> 2, seg = tid & 3;
    const unsigned short* src = qkv + (size_t)(t0 + tr) * QKV_OUT + Q_SIZE + KV_SIZE +
                                kvh * 128 + db + seg * 16;
    us4* drow = (us4*)&tile[tr][seg * 16];
#pragma unroll
    for (int q = 0; q < 4; ++q) drow[q] = ((const us4*)src)[q];
    __syncthreads();
    int dr = tid >> 2;
    unsigned short* dst = vT + ((size_t)kvh * 128 + db + dr) * N_TOK + t0 + seg * 16;
    unsigned short buf[16];
#pragma unroll
    for (int j = 0; j < 16; ++j) buf[j] = tile[seg * 16 + j][dr];
#pragma unroll
    for (int q = 0; q < 4; ++q) ((us4*)dst)[q] = ((us4*)buf)[q];
}

// ------ flash attention, fixed-max softmax, stage-early K/V prefetch ------
// K/V tile loads are issued right after the LDS write of the previous tile
// (same registers, no extra VGPR) so global latency hides under QK^T+PV.
__global__ __launch_bounds__(256) void k_attn(
        const unsigned short* __restrict__ qb,
        const unsigned short* __restrict__ kb,
        const unsigned short* __restrict__ vT,
        const float* __restrict__ gate,
        unsigned short* __restrict__ og) {
    int bid = blockIdx.x;
    int tid = threadIdx.x;
    int qt = bid & 15, qh = bid >> 4, kvh = qh / 5;
    int w = tid >> 6, l = tid & 63;
    int q0 = qt * 128 + w * 32;
    __shared__ __align__(16) char smem[49152];
    char* Ks = smem;
    char* Vs = smem + 16384;
    char* Ps = smem + 32768 + w * 4096;

    bf16x8 qf[2][4];
#pragma unroll
    for (int mi = 0; mi < 2; ++mi)
#pragma unroll
        for (int ks = 0; ks < 4; ++ks)
            qf[mi][ks] = *(const bf16x8*)(qb + (size_t)(q0 + mi * 16 + (l & 15)) * Q_SIZE +
                                          qh * 128 + ks * 32 + (l >> 4) * 8);

    f32x4 oacc[2][8] = {};
    f32x4 psum[2] = {};

    int kr = tid >> 2, kseg = tid & 3;
    int vr = tid >> 1, vh2 = tid & 1;
    const unsigned short* ksrc0 = kb + (size_t)kr * KV_SIZE + kvh * 128 + kseg * 32;
    const unsigned short* vsrc0 = vT + ((size_t)kvh * 128 + vr) * N_TOK + vh2 * 32;

    bf16x8 kv4[4], vv4[4];
#pragma unroll
    for (int q = 0; q < 4; ++q) {           // tile 0
        kv4[q] = *(const bf16x8*)(ksrc0 + q * 8);
        vv4[q] = *(const bf16x8*)(vsrc0 + q * 8);
    }

#pragma unroll 1
    for (int kt = 0; kt < 32; ++kt) {
        __syncthreads();                    // prev compute done reading LDS
#pragma unroll
        for (int q = 0; q < 4; ++q) {
            *(bf16x8*)(Ks + kr * 256 + ((((kseg * 4 + q) * 16)) ^ ((kr & 7) << 4))) = kv4[q];
            *(bf16x8*)(Vs + vr * 128 + ((((vh2 * 4 + q) * 16)) ^ ((vr & 7) << 4))) = vv4[q];
        }
        __syncthreads();
        // prefetch next tile into the same regs; lands during compute below
        if (kt + 1 < 32) {
            const unsigned short* ksrc = ksrc0 + (size_t)(kt + 1) * 64 * KV_SIZE;
            const unsigned short* vsrc = vsrc0 + (kt + 1) * 64;
#pragma unroll
            for (int q = 0; q < 4; ++q) {
                kv4[q] = *(const bf16x8*)(ksrc + q * 8);
                vv4[q] = *(const bf16x8*)(vsrc + q * 8);
            }
        }
        // S = Q K^T
        f32x4 s[2][4] = {};
#pragma unroll
        for (int ks = 0; ks < 4; ++ks) {
            bf16x8 kf[4];
#pragma unroll
            for (int ni = 0; ni < 4; ++ni) {
                int row = ni * 16 + (l & 15);
                kf[ni] = *(const bf16x8*)(Ks + row * 256 +
                            ((ks * 64 + (l >> 4) * 16) ^ ((row & 7) << 4)));
            }
#pragma unroll
            for (int mi = 0; mi < 2; ++mi)
#pragma unroll
                for (int ni = 0; ni < 4; ++ni)
                    s[mi][ni] = mfma16(qf[mi][ks], kf[ni], s[mi][ni]);
        }
        // p = exp2(s); per-lane row-sum accumulate; bf16 P to wave-private LDS.
#pragma unroll
        for (int mi = 0; mi < 2; ++mi)
#pragma unroll
            for (int ni = 0; ni < 4; ++ni) {
#pragma unroll
                for (int r = 0; r < 4; ++r) {
                    float p = exp2f(s[mi][ni][r]);
                    psum[mi][r] += p;
                    int qr = mi * 16 + ((l >> 4) << 2) + r;
                    int tcb = (ni * 16 + (l & 15)) * 2;
                    *(unsigned short*)(Ps + qr * 128 +
                        (tcb ^ (((qr >> 2) & 3) << 5))) = f2bf(p);
                }
            }
        // O += P V
#pragma unroll
        for (int ks = 0; ks < 2; ++ks) {
            bf16x8 pa[2];
#pragma unroll
            for (int mi = 0; mi < 2; ++mi) {
                int qr = mi * 16 + (l & 15);
                pa[mi] = *(const bf16x8*)(Ps + qr * 128 +
                            ((ks * 64 + (l >> 4) * 16) ^ (((qr >> 2) & 3) << 5)));
            }
#pragma unroll
            for (int nd = 0; nd < 8; ++nd) {
                int row = nd * 16 + (l & 15);
                bf16x8 vf = *(const bf16x8*)(Vs + row * 128 +
                            ((ks * 64 + (l >> 4) * 16) ^ ((row & 7) << 4)));
#pragma unroll
                for (int mi = 0; mi < 2; ++mi)
                    oacc[mi][nd] = mfma16(pa[mi], vf, oacc[mi][nd]);
            }
        }
    }
    // deferred row-sum reduce: rows live in 16-lane groups (same l>>4)
#pragma unroll
    for (int mi = 0; mi < 2; ++mi)
#pragma unroll
        for (int r = 0; r < 4; ++r) {
            float v = psum[mi][r];
            v += __shfl_xor(v, 1);
            v += __shfl_xor(v, 2);
            v += __shfl_xor(v, 4);
            v += __shfl_xor(v, 8);
            psum[mi][r] = v;
        }
#pragma unroll
    for (int mi = 0; mi < 2; ++mi)
#pragma unroll
        for (int r = 0; r < 4; ++r) {
            int row = q0 + mi * 16 + ((l >> 4) << 2) + r;
            float sc = (1.f / psum[mi][r]) * gate[(size_t)row * HQ + qh];
#pragma unroll
            for (int nd = 0; nd < 8; ++nd)
                og[(size_t)row * Q_SIZE + qh * 128 + nd * 16 + (l & 15)] =
                    f2bf(oacc[mi][nd][r] * sc);
        }
}

extern "C" void kernel_launch(void* const* d_in, const int* in_sizes, int n_in,
                              void* d_out, int out_size, void* d_ws, size_t ws_size,
                              hipStream_t stream) {
    const float* hidden = (const float*)d_in[0];
    const float* rope   = (const float*)d_in[1];
    const float* pnw    = (const float*)d_in[2];
    const float* qkvw   = (const float*)d_in[3];
    const float* qnw    = (const float*)d_in[4];
    const float* knw    = (const float*)d_in[5];
    const float* projw  = (const float*)d_in[6];
    const int*   mids   = (const int*)d_in[7];
    float* out = (float*)d_out;

    char* ws = (char*)d_ws;
    const size_t nqkvw = (size_t)3 * QKV_OUT * HIDDEN;
    const size_t nprojw = (size_t)3 * HIDDEN * Q_SIZE;
    const size_t wbytes = (nqkvw + nprojw) * 2;

    const size_t small_bytes = 16384 +
        (size_t)N_TOK * HIDDEN * 2 +      // h
        (size_t)N_TOK * QKV_OUT * 2 +     // qkv
        (size_t)N_TOK * Q_SIZE * 2 +      // qb
        (size_t)N_TOK * KV_SIZE * 2 +     // kb
        (size_t)N_TOK * KV_SIZE * 2 +     // vT
        (size_t)N_TOK * Q_SIZE * 2 +      // og
        (size_t)N_TOK * HQ * 4;           // gate
    bool use_bf = (ws_size >= wbytes + small_bytes);
    if (!use_bf && ws_size < small_bytes) return;  // loud failure

    unsigned short* wqkv = (unsigned short*)ws;
    unsigned short* wproj = wqkv + nqkvw;
    char* sb = ws + (use_bf ? wbytes : 0);

    int* meta = (int*)sb;
    int* perm = (int*)(sb + 64);
    unsigned short* h   = (unsigned short*)(sb + 16384);
    unsigned short* qkv = h   + (size_t)N_TOK * HIDDEN;
    unsigned short* qb  = qkv + (size_t)N_TOK * QKV_OUT;
    unsigned short* kb  = qb  + (size_t)N_TOK * Q_SIZE;
    unsigned short* vT  = kb  + (size_t)N_TOK * KV_SIZE;
    unsigned short* og  = vT  + (size_t)N_TOK * KV_SIZE;
    float* gate = (float*)(og + (size_t)N_TOK * Q_SIZE);

    k_sort<<<1, 64, 0, stream>>>(mids, meta, perm);
    if (use_bf) {
        // prenorm + qkv-weight cvt overlapped in one dispatch
        k_prenorm_cvt<<<2048 + 1024, 256, 0, stream>>>(
            hidden, pnw, meta, perm, h, qkvw, wqkv, (int)(nqkvw / 8));
        // QKV GEMM + proj-weight cvt overlapped (GEMM leaves HBM pipe idle)
        k_gemm<QKV_OUT, false><<<16 * 57 * 3 + 1024, 256, 0, stream>>>(
            h, wqkv, qkv, nullptr, meta, perm, 16, 57,
            projw, wproj, (int)(nprojw / 8));
        k_qknorm<<<2048, 256, 0, stream>>>(qkv, rope, qnw, knw, meta, perm, qb, kb, gate);
        k_vtrans<<<dim3(32, 2, 8), 256, 0, stream>>>(qkv, vT);
        k_attn<<<640, 256, 0, stream>>>(qb, kb, vT, gate, og);
        k_gemm2<HIDDEN, true><<<16 * 20 * 3, 256, 0, stream>>>(
            og, wproj, nullptr, out, meta, perm, 16, 20);
    } else {
        k_prenorm_cvt<<<2048, 256, 0, stream>>>(
            hidden, pnw, meta, perm, h, nullptr, nullptr, 0);
        k_moe_gemm<QKV_OUT, false><<<dim3(57, 16, 3), 256, 0, stream>>>(
            h, qkvw, qkv, nullptr, meta, perm);
        k_qknorm<<<2048, 256, 0, stream>>>(qkv, rope, qnw, knw, meta, perm, qb, kb, gate);
        k_vtrans<<<dim3(32, 2, 8), 256, 0, stream>>>(qkv, vT);
        k_attn<<<640, 256, 0, stream>>>(qb, kb, vT, gate, og);
        k_moe_gemm<HIDDEN, true><<<dim3(40, 16, 3), 256, 0, stream>>>(
            og, projw, nullptr, out, meta, perm);
    }
}